// Round 3
// baseline (2371.317 us; speedup 1.0000x reference)
//
#include <hip/hip_runtime.h>
#include <stdint.h>

#define NB 8
#define NN 4096
#define NC 64
#define NS 1024
#define NK 32
#define NQ (NB*NS)        /* 8192 queries */
#define NP (NQ*NK)        /* 262144 positions */
#define EPSBN 1e-5f

typedef unsigned long long u64;

__device__ __forceinline__ float lrelu(float x){ return x >= 0.0f ? x : 0.1f*x; }

// IEEE-total-order key: ascending key == ascending float
__device__ __forceinline__ unsigned int fkey(float d){
    unsigned int fb = __float_as_uint(d);
    return (fb & 0x80000000u) ? ~fb : (fb | 0x80000000u);
}

// ---- DPP wave(64) helpers -------------------------------------------------
__device__ __forceinline__ float wave_max_f(float x){
    int v = __float_as_int(x);
    {int o=__builtin_amdgcn_update_dpp(v,v,0x111,0xf,0xf,false); v=__float_as_int(fmaxf(__int_as_float(v),__int_as_float(o)));}
    {int o=__builtin_amdgcn_update_dpp(v,v,0x112,0xf,0xf,false); v=__float_as_int(fmaxf(__int_as_float(v),__int_as_float(o)));}
    {int o=__builtin_amdgcn_update_dpp(v,v,0x114,0xf,0xf,false); v=__float_as_int(fmaxf(__int_as_float(v),__int_as_float(o)));}
    {int o=__builtin_amdgcn_update_dpp(v,v,0x118,0xf,0xf,false); v=__float_as_int(fmaxf(__int_as_float(v),__int_as_float(o)));}
    {int o=__builtin_amdgcn_update_dpp(v,v,0x142,0xf,0xf,false); v=__float_as_int(fmaxf(__int_as_float(v),__int_as_float(o)));}
    {int o=__builtin_amdgcn_update_dpp(v,v,0x143,0xf,0xf,false); v=__float_as_int(fmaxf(__int_as_float(v),__int_as_float(o)));}
    return __int_as_float(__builtin_amdgcn_readlane(v, 63));
}
// sum-reduce (valid on lane 63 only)
__device__ __forceinline__ float wave_sum_f(float x){
    int v = __float_as_int(x);
    {int o=__builtin_amdgcn_update_dpp(0,v,0x111,0xf,0xf,true); v=__float_as_int(__int_as_float(v)+__int_as_float(o));}
    {int o=__builtin_amdgcn_update_dpp(0,v,0x112,0xf,0xf,true); v=__float_as_int(__int_as_float(v)+__int_as_float(o));}
    {int o=__builtin_amdgcn_update_dpp(0,v,0x114,0xf,0xf,true); v=__float_as_int(__int_as_float(v)+__int_as_float(o));}
    {int o=__builtin_amdgcn_update_dpp(0,v,0x118,0xf,0xf,true); v=__float_as_int(__int_as_float(v)+__int_as_float(o));}
    {int o=__builtin_amdgcn_update_dpp(0,v,0x142,0xf,0xf,true); v=__float_as_int(__int_as_float(v)+__int_as_float(o));}
    {int o=__builtin_amdgcn_update_dpp(0,v,0x143,0xf,0xf,true); v=__float_as_int(__int_as_float(v)+__int_as_float(o));}
    return __int_as_float(v);
}
// inclusive prefix-sum over 64 lanes (ints)
__device__ __forceinline__ int wave_incl_add(int x){
    int v = x;
    {int o=__builtin_amdgcn_update_dpp(0,v,0x111,0xf,0xf,true); v+=o;}
    {int o=__builtin_amdgcn_update_dpp(0,v,0x112,0xf,0xf,true); v+=o;}
    {int o=__builtin_amdgcn_update_dpp(0,v,0x114,0xf,0xf,true); v+=o;}
    {int o=__builtin_amdgcn_update_dpp(0,v,0x118,0xf,0xf,true); v+=o;}
    {int o=__builtin_amdgcn_update_dpp(0,v,0x142,0xa,0xf,true); v+=o;}
    {int o=__builtin_amdgcn_update_dpp(0,v,0x143,0xc,0xf,true); v+=o;}
    return v;
}

// ---------------------------------------------------------------------------
// FPS: one block/batch, 512 thr, 8 contiguous pts/thread in regs.
// No global traffic in the serial loop (sFar LDS journal, writeback at end).
// Winner coords travel through the LDS slot -> no dependent sX[far] read.
// Bit-exact vs numpy: rn ops, ((dx2+dy2)+dz2), fminf, argmax first-occurrence.
// ---------------------------------------------------------------------------
__global__ __launch_bounds__(512) void fps_kernel(const float* __restrict__ xyz,
                                                  float* __restrict__ out0,
                                                  float* __restrict__ nxyz)
{
    __shared__ float sX[NN], sY[NN], sZ[NN];
    __shared__ u64    slotsK[2][8];
    __shared__ float4 slotsC[2][8];
    __shared__ int    sFar[NS];
    const int b = blockIdx.x, t = threadIdx.x;
    const int lane = t & 63, wv = t >> 6;
    const float* base = xyz + (size_t)b*NN*3;
    for (int i = t; i < NN; i += 512){
        const float* pp = base + 3*i;
        sX[i] = pp[0]; sY[i] = pp[1]; sZ[i] = pp[2];
    }
    __syncthreads();
    float px[8], py[8], pz[8], dist[8];
    const int pb = t*8;
    #pragma unroll
    for (int j = 0; j < 8; ++j){
        px[j]=sX[pb+j]; py[j]=sY[pb+j]; pz[j]=sZ[pb+j]; dist[j]=1e10f;
    }
    int far = 0;
    float cx = sX[0], cy = sY[0], cz = sZ[0];
    for (int s = 0; s < NS; ++s){
        if (t == 0) sFar[s] = far;
        float best = -1.0f; int jb = 0;
        float bx = px[0], by = py[0], bz = pz[0];
        #pragma unroll
        for (int j = 0; j < 8; ++j){
            float dx=__fsub_rn(px[j],cx), dy=__fsub_rn(py[j],cy), dz=__fsub_rn(pz[j],cz);
            float dd=__fadd_rn(__fadd_rn(__fmul_rn(dx,dx),__fmul_rn(dy,dy)),__fmul_rn(dz,dz));
            float nd = fminf(dist[j], dd);
            dist[j] = nd;
            if (nd > best){ best = nd; jb = j; bx = px[j]; by = py[j]; bz = pz[j]; }
        }
        float wmax = wave_max_f(best);
        u64 mask = __ballot(best == wmax);
        int L = __ffsll(mask) - 1;                 // lowest lane = smallest idx
        const int par = s & 1;
        if (lane == L){
            u64 pk = ((u64)fkey(wmax) << 32) | (u64)(0xFFFFFFFFu - (unsigned)(pb + jb));
            slotsK[par][wv] = pk;
            slotsC[par][wv] = make_float4(bx, by, bz, 0.0f);
        }
        __syncthreads();
        u64 ka[8]; float4 ca[8];
        #pragma unroll
        for (int k = 0; k < 8; ++k){ ka[k] = slotsK[par][k]; ca[k] = slotsC[par][k]; }
        #pragma unroll
        for (int st = 4; st >= 1; st >>= 1){
            #pragma unroll
            for (int k = 0; k < 8; ++k){
                if (k < st && ka[k+st] > ka[k]){ ka[k] = ka[k+st]; ca[k] = ca[k+st]; }
            }
        }
        far = (int)(0xFFFFFFFFu - (unsigned)(ka[0] & 0xFFFFFFFFull));
        cx = ca[0].x; cy = ca[0].y; cz = ca[0].z;
    }
    __syncthreads();
    for (int s = t; s < NS; s += 512){
        const int f = sFar[s];
        const float x = sX[f], y = sY[f], z = sZ[f];
        float* npq = nxyz + ((size_t)b*NS + s)*3;
        npq[0]=x; npq[1]=y; npq[2]=z;
        out0[(b*3+0)*NS+s]=x; out0[(b*3+1)*NS+s]=y; out0[(b*3+2)*NS+s]=z;
    }
}

// ---------------------------------------------------------------------------
// KNN: one wave per query; exact 32nd-smallest via 32-level bitwise binary
// search on fkey (pure VALU + DPP reduce, no LDS, no atomics). Ties at the
// threshold resolved by smallest index (matches lax.top_k on -d).
// ---------------------------------------------------------------------------
__global__ __launch_bounds__(256) void knn_kernel(const float* __restrict__ xyz,
                                                  const float* __restrict__ nxyz,
                                                  int* __restrict__ kidx)
{
    const int t = threadIdx.x, lane = t & 63, w = t >> 6;
    const int q = blockIdx.x*4 + w;
    const int b = q >> 10;
    const float* base = xyz + (size_t)b*NN*3;
    const float* qp = nxyz + (size_t)q*3;
    const float qx = qp[0], qy = qp[1], qz = qp[2];
    const float qsq = __fadd_rn(__fadd_rn(__fmul_rn(qx,qx),__fmul_rn(qy,qy)),__fmul_rn(qz,qz));

    unsigned int key[64];
    #pragma unroll
    for (int i = 0; i < 64; ++i){
        const int idx = (i<<6) + lane;
        const float* pp = base + 3*idx;
        float x = pp[0], y = pp[1], z = pp[2];
        float dot = __fadd_rn(__fadd_rn(__fmul_rn(qx,x),__fmul_rn(qy,y)),__fmul_rn(qz,z));
        float psq = __fadd_rn(__fadd_rn(__fmul_rn(x,x),__fmul_rn(y,y)),__fmul_rn(z,z));
        float d = __fadd_rn(__fadd_rn(__fmul_rn(-2.0f,dot),qsq),psq);
        key[i] = fkey(d);
    }

    // binary search for the 32nd smallest key
    unsigned int pref = 0; int need = 32;
    for (int bit = 31; bit >= 0; --bit){
        const unsigned int bound = 1u << bit;
        int c = 0;
        #pragma unroll
        for (int i = 0; i < 64; ++i) c += ((key[i] ^ pref) < bound) ? 1 : 0;
        int tot = __builtin_amdgcn_readlane(wave_incl_add(c), 63);
        if (tot < need){ need -= tot; pref |= bound; }
    }
    const unsigned int T = pref;

    // emission: all keys < T, plus first `need` keys == T in ascending idx
    int cl = 0;
    #pragma unroll
    for (int i = 0; i < 64; ++i) cl += (key[i] < T) ? 1 : 0;
    int incl_cl = wave_incl_add(cl);
    int clx = incl_cl - cl;
    int tiebase = __builtin_amdgcn_readlane(incl_cl, 63);
    int* oq = kidx + (size_t)q*NK;
    int pos = clx;
    #pragma unroll
    for (int i = 0; i < 64; ++i){
        if (key[i] < T){ oq[pos] = (i<<6) + lane; ++pos; }
    }
    int tcount = 0;
    for (int i = 0; i < 64 && tcount < need; ++i){
        u64 m = __ballot(key[i] == T);
        int myrank = (int)__popcll(m & ((1ull << lane) - 1ull));
        if ((key[i] == T) && (tcount + myrank < need))
            oq[tiebase + tcount + myrank] = (i<<6) + lane;
        tcount += (int)__popcll(m);
    }
}

// ---------------------------------------------------------------------------
// Gather: x0[c][p] = features[b, kidx[p], c]   (layout [C, NP])
// ---------------------------------------------------------------------------
__global__ __launch_bounds__(256) void gather_kernel(const float* __restrict__ features,
                                                     const int* __restrict__ kidx,
                                                     float* __restrict__ x0)
{
    const int p = blockIdx.x*256 + threadIdx.x;
    const int b = p >> 15;
    const int idx = kidx[p];
    const float4* f = (const float4*)(features + ((size_t)b*NN + idx)*NC);
    #pragma unroll
    for (int c4 = 0; c4 < 16; ++c4){
        float4 v = f[c4];
        x0[(size_t)(4*c4+0)*NP + p] = v.x;
        x0[(size_t)(4*c4+1)*NP + p] = v.y;
        x0[(size_t)(4*c4+2)*NP + p] = v.z;
        x0[(size_t)(4*c4+3)*NP + p] = v.w;
    }
}

// ---------------------------------------------------------------------------
// Conv 1x1 (+ optional folded BN-affine + leaky on INPUT). Pure GEMM pass.
// ---------------------------------------------------------------------------
__global__ __launch_bounds__(512) void conv_kernel(const float* __restrict__ in,
    float* __restrict__ out, const float* __restrict__ W, const float* __restrict__ bias,
    const float* __restrict__ aff, const int apply_act)
{
    __shared__ __align__(16) float sWt[64*64];   // [c][o]
    __shared__ float sSc[64], sSh[64], sB[64];
    const int t = threadIdx.x;
    for (int i = t; i < 4096; i += 512){
        int o = i >> 6, c = i & 63;
        sWt[c*64 + o] = W[i];
    }
    if (t < 64){
        sB[t] = bias[t];
        if (apply_act){ sSc[t] = aff[t]; sSh[t] = aff[64+t]; }
        else          { sSc[t] = 1.0f;  sSh[t] = 0.0f; }
    }
    __syncthreads();
    const int lane = t & 63;
    const int wv = t >> 6;
    const int obase = (wv >> 2) * 32;
    const int p0 = blockIdx.x*1024 + (wv & 3)*64 + lane;
    float acc[4][32];
    #pragma unroll
    for (int o = 0; o < 32; ++o){
        float bb = sB[obase + o];
        acc[0][o]=bb; acc[1][o]=bb; acc[2][o]=bb; acc[3][o]=bb;
    }
    #pragma unroll 8
    for (int c = 0; c < 64; ++c){
        float xv[4];
        xv[0] = in[(size_t)c*NP + p0];
        xv[1] = in[(size_t)c*NP + p0 + 256];
        xv[2] = in[(size_t)c*NP + p0 + 512];
        xv[3] = in[(size_t)c*NP + p0 + 768];
        if (apply_act){
            float sc = sSc[c], sh = sSh[c];
            #pragma unroll
            for (int j = 0; j < 4; ++j){
                float v = fmaf(sc, xv[j], sh);
                xv[j] = v >= 0.0f ? v : 0.1f*v;
            }
        }
        const float4* wr = (const float4*)(sWt + c*64 + obase);
        #pragma unroll
        for (int o4 = 0; o4 < 8; ++o4){
            float4 wvv = wr[o4];
            #pragma unroll
            for (int j = 0; j < 4; ++j){
                acc[j][4*o4+0] = fmaf(wvv.x, xv[j], acc[j][4*o4+0]);
                acc[j][4*o4+1] = fmaf(wvv.y, xv[j], acc[j][4*o4+1]);
                acc[j][4*o4+2] = fmaf(wvv.z, xv[j], acc[j][4*o4+2]);
                acc[j][4*o4+3] = fmaf(wvv.w, xv[j], acc[j][4*o4+3]);
            }
        }
    }
    #pragma unroll
    for (int o = 0; o < 32; ++o){
        float* po = out + (size_t)(obase+o)*NP + p0;
        po[0]   = acc[0][o];
        po[256] = acc[1][o];
        po[512] = acc[2][o];
        po[768] = acc[3][o];
    }
}

// ---------------------------------------------------------------------------
// BN stats: block = (channel, chunk of 8192); coalesced float4, DPP reduce.
// ---------------------------------------------------------------------------
__global__ __launch_bounds__(256) void stats_kernel(const float* __restrict__ buf,
                                                    float* __restrict__ partials)
{
    __shared__ float red[8];
    const int t = threadIdx.x, lane = t & 63, wv = t >> 6;
    const int c = blockIdx.x >> 5, chunk = blockIdx.x & 31;
    const float4* p4 = (const float4*)(buf + (size_t)c*NP + (size_t)chunk*8192) + t;
    float s1 = 0.0f, s2 = 0.0f;
    #pragma unroll
    for (int i = 0; i < 8; ++i){
        float4 v = p4[i*256];
        s1 += v.x + v.y + v.z + v.w;
        s2 += v.x*v.x + v.y*v.y + v.z*v.z + v.w*v.w;
    }
    float t1 = wave_sum_f(s1), t2 = wave_sum_f(s2);
    if (lane == 63){ red[wv*2] = t1; red[wv*2+1] = t2; }
    __syncthreads();
    if (t == 0){
        partials[blockIdx.x]        = red[0]+red[2]+red[4]+red[6];
        partials[2048 + blockIdx.x] = red[1]+red[3]+red[5]+red[7];
    }
}

// ---------------------------------------------------------------------------
__global__ __launch_bounds__(64) void finalize_kernel(const float* __restrict__ partials,
    const float* __restrict__ g, const float* __restrict__ beta, float* __restrict__ aff)
{
    const int t = threadIdx.x;   // t = channel
    float S1 = 0.0f, S2 = 0.0f;
    #pragma unroll 8
    for (int i = 0; i < 32; ++i){
        S1 += partials[t*32 + i];
        S2 += partials[2048 + t*32 + i];
    }
    float mean = S1 * (1.0f/(float)NP);
    float var  = fmaxf(S2 * (1.0f/(float)NP) - mean*mean, 0.0f);
    float sc = g[t] * rsqrtf(var + EPSBN);
    aff[t]    = sc;
    aff[64+t] = beta[t] - mean*sc;
}

// ---------------------------------------------------------------------------
__global__ __launch_bounds__(256) void resid_kernel(const float* __restrict__ v,
    const float* __restrict__ yt, float* __restrict__ x2,
    const float* __restrict__ affV, const float* __restrict__ affY)
{
    const size_t e = (size_t)blockIdx.x*256 + threadIdx.x;
    const int c = (int)(e >> 16);
    const float va = affV[c], vb = affV[64+c];
    const float ya = affY[c], yb = affY[64+c];
    const float4 vv = ((const float4*)v)[e];
    const float4 yy = ((const float4*)yt)[e];
    float4 r;
    r.x = lrelu(fmaf(va, vv.x, vb) + lrelu(fmaf(ya, yy.x, yb)));
    r.y = lrelu(fmaf(va, vv.y, vb) + lrelu(fmaf(ya, yy.y, yb)));
    r.z = lrelu(fmaf(va, vv.z, vb) + lrelu(fmaf(ya, yy.z, yb)));
    r.w = lrelu(fmaf(va, vv.w, vb) + lrelu(fmaf(ya, yy.w, yb)));
    ((float4*)x2)[e] = r;
}

// ---------------------------------------------------------------------------
__global__ __launch_bounds__(256) void final_kernel(const float* __restrict__ v2,
    const float* __restrict__ x2, const float* __restrict__ aff, float* __restrict__ out1)
{
    const int gg = blockIdx.x*256 + threadIdx.x;
    const int c = gg >> 13;
    const int bs = gg & 8191;
    const float a = aff[c], sh = aff[64+c];
    const float4* pv = (const float4*)(v2 + (size_t)c*NP + (size_t)bs*NK);
    const float4* px = (const float4*)(x2 + (size_t)c*NP + (size_t)bs*NK);
    float m = -3.0e38f;
    #pragma unroll
    for (int i = 0; i < 8; ++i){
        float4 av = pv[i], xv = px[i];
        m = fmaxf(m, lrelu(fmaf(a, av.x, sh) + xv.x));
        m = fmaxf(m, lrelu(fmaf(a, av.y, sh) + xv.y));
        m = fmaxf(m, lrelu(fmaf(a, av.z, sh) + xv.z));
        m = fmaxf(m, lrelu(fmaf(a, av.w, sh) + xv.w));
    }
    const int b = bs >> 10, s = bs & 1023;
    out1[((size_t)b*NC + c)*NS + s] = m;
}

// ---------------------------------------------------------------------------
extern "C" void kernel_launch(void* const* d_in, const int* in_sizes, int n_in,
                              void* d_out, int out_size, void* d_ws, size_t ws_size,
                              hipStream_t stream)
{
    const float* xyz      = (const float*)d_in[0];
    const float* features = (const float*)d_in[1];
    const float* w_t    = (const float*)d_in[2];
    const float* w1_0   = (const float*)d_in[3];
    const float* w2_0   = (const float*)d_in[4];
    const float* w1_1   = (const float*)d_in[5];
    const float* w2_1   = (const float*)d_in[6];
    const float* b_t    = (const float*)d_in[7];
    const float* b1_0   = (const float*)d_in[8];
    const float* b2_0   = (const float*)d_in[9];
    const float* b1_1   = (const float*)d_in[10];
    const float* b2_1   = (const float*)d_in[11];
    const float* g_t    = (const float*)d_in[12];
    const float* g1_0   = (const float*)d_in[13];
    const float* g2_0   = (const float*)d_in[14];
    const float* g1_1   = (const float*)d_in[15];
    const float* g2_1   = (const float*)d_in[16];
    const float* beta_t  = (const float*)d_in[17];
    const float* beta1_0 = (const float*)d_in[18];
    const float* beta2_0 = (const float*)d_in[19];
    const float* beta1_1 = (const float*)d_in[20];
    const float* beta2_1 = (const float*)d_in[21];

    float* out = (float*)d_out;

    float* buf0  = (float*)d_ws;
    float* buf1  = buf0 + (size_t)NC*NP;
    float* buf2  = buf1 + (size_t)NC*NP;
    float* nxyz  = buf2 + (size_t)NC*NP;                 // NB*NS*3
    int*   kidx  = (int*)(nxyz + (size_t)NB*NS*3);       // NP ints
    float* partials = (float*)(kidx + NP);               // 4096 floats
    float* affx  = partials + 4096;                      // 5*128

    fps_kernel<<<NB, 512, 0, stream>>>(xyz, out, nxyz);
    knn_kernel<<<NQ/4, 256, 0, stream>>>(xyz, nxyz, kidx);
    gather_kernel<<<NP/256, 256, 0, stream>>>(features, kidx, buf0);

    // stage t
    conv_kernel<<<NP/1024, 512, 0, stream>>>(buf0, buf1, w_t, b_t, affx, 0);
    stats_kernel<<<2048, 256, 0, stream>>>(buf1, partials);
    finalize_kernel<<<1, 64, 0, stream>>>(partials, g_t, beta_t, affx + 0);
    // resblock 0
    conv_kernel<<<NP/1024, 512, 0, stream>>>(buf1, buf0, w1_0, b1_0, affx + 0, 1);
    stats_kernel<<<2048, 256, 0, stream>>>(buf0, partials);
    finalize_kernel<<<1, 64, 0, stream>>>(partials, g1_0, beta1_0, affx + 128);
    conv_kernel<<<NP/1024, 512, 0, stream>>>(buf0, buf2, w2_0, b2_0, affx + 128, 1);
    stats_kernel<<<2048, 256, 0, stream>>>(buf2, partials);
    finalize_kernel<<<1, 64, 0, stream>>>(partials, g2_0, beta2_0, affx + 256);
    resid_kernel<<<(NC*NP/4)/256, 256, 0, stream>>>(buf2, buf1, buf0, affx + 256, affx + 0);
    // resblock 1
    conv_kernel<<<NP/1024, 512, 0, stream>>>(buf0, buf1, w1_1, b1_1, affx, 0);
    stats_kernel<<<2048, 256, 0, stream>>>(buf1, partials);
    finalize_kernel<<<1, 64, 0, stream>>>(partials, g1_1, beta1_1, affx + 384);
    conv_kernel<<<NP/1024, 512, 0, stream>>>(buf1, buf2, w2_1, b2_1, affx + 384, 1);
    stats_kernel<<<2048, 256, 0, stream>>>(buf2, partials);
    finalize_kernel<<<1, 64, 0, stream>>>(partials, g2_1, beta2_1, affx + 512);
    // epilogue: residual + max over K
    final_kernel<<<(NC*NQ)/256, 256, 0, stream>>>(buf2, buf0, affx + 512, out + (size_t)NB*3*NS);
}

// Round 4
// 1326.954 us; speedup vs baseline: 1.7870x; 1.7870x over previous
//
#include <hip/hip_runtime.h>
#include <stdint.h>

#define NB 8
#define NN 4096
#define NC 64
#define NS 1024
#define NK 32
#define NQ (NB*NS)        /* 8192 queries */
#define NP (NQ*NK)        /* 262144 positions */
#define EPSBN 1e-5f

typedef unsigned long long u64;

__device__ __forceinline__ float lrelu(float x){ return x >= 0.0f ? x : 0.1f*x; }

// IEEE-total-order key: ascending key == ascending float
__device__ __forceinline__ unsigned int fkey(float d){
    unsigned int fb = __float_as_uint(d);
    return (fb & 0x80000000u) ? ~fb : (fb | 0x80000000u);
}

// sum-reduce (valid on lane 63 only)
__device__ __forceinline__ float wave_sum_f(float x){
    int v = __float_as_int(x);
    {int o=__builtin_amdgcn_update_dpp(0,v,0x111,0xf,0xf,true); v=__float_as_int(__int_as_float(v)+__int_as_float(o));}
    {int o=__builtin_amdgcn_update_dpp(0,v,0x112,0xf,0xf,true); v=__float_as_int(__int_as_float(v)+__int_as_float(o));}
    {int o=__builtin_amdgcn_update_dpp(0,v,0x114,0xf,0xf,true); v=__float_as_int(__int_as_float(v)+__int_as_float(o));}
    {int o=__builtin_amdgcn_update_dpp(0,v,0x118,0xf,0xf,true); v=__float_as_int(__int_as_float(v)+__int_as_float(o));}
    {int o=__builtin_amdgcn_update_dpp(0,v,0x142,0xf,0xf,true); v=__float_as_int(__int_as_float(v)+__int_as_float(o));}
    {int o=__builtin_amdgcn_update_dpp(0,v,0x143,0xf,0xf,true); v=__float_as_int(__int_as_float(v)+__int_as_float(o));}
    return __int_as_float(v);
}
// inclusive prefix-sum over 64 lanes (ints)
__device__ __forceinline__ int wave_incl_add(int x){
    int v = x;
    {int o=__builtin_amdgcn_update_dpp(0,v,0x111,0xf,0xf,true); v+=o;}
    {int o=__builtin_amdgcn_update_dpp(0,v,0x112,0xf,0xf,true); v+=o;}
    {int o=__builtin_amdgcn_update_dpp(0,v,0x114,0xf,0xf,true); v+=o;}
    {int o=__builtin_amdgcn_update_dpp(0,v,0x118,0xf,0xf,true); v+=o;}
    {int o=__builtin_amdgcn_update_dpp(0,v,0x142,0xa,0xf,true); v+=o;}
    {int o=__builtin_amdgcn_update_dpp(0,v,0x143,0xc,0xf,true); v+=o;}
    return v;
}

// ---------------------------------------------------------------------------
// FPS: one block/batch, 256 thr (4 waves = 1/SIMD), 16 pts/thread in regs.
// Per-lane argmax via f64 packed max: double{hi=dist_bits, lo=~idx} —
// positive doubles, monotone in (dist, -idx) => first-occurrence argmax.
// Wave reduce: u64 shfl_xor butterfly. Cross-wave: 4 u64 LDS slots.
// Bit-exact vs numpy: rn ops, ((dx2+dy2)+dz2), fminf.
// ---------------------------------------------------------------------------
__global__ __launch_bounds__(256,1) void fps_kernel(const float* __restrict__ xyz,
                                                    float* __restrict__ out0,
                                                    float* __restrict__ nxyz)
{
    __shared__ float sX[NN], sY[NN], sZ[NN];
    __shared__ u64 slots[2][4];
    __shared__ int sFar[NS];
    const int b = blockIdx.x, t = threadIdx.x;
    const int wv = t >> 6;
    const float* base = xyz + (size_t)b*NN*3;
    for (int i = t; i < NN; i += 256){
        const float* pp = base + 3*i;
        sX[i] = pp[0]; sY[i] = pp[1]; sZ[i] = pp[2];
    }
    __syncthreads();
    float px[16], py[16], pz[16], dist[16];
    const int pb = t*16;
    #pragma unroll
    for (int j = 0; j < 16; ++j){
        px[j]=sX[pb+j]; py[j]=sY[pb+j]; pz[j]=sZ[pb+j]; dist[j]=1e10f;
    }
    int far = 0;
    float cx = sX[0], cy = sY[0], cz = sZ[0];
    for (int s = 0; s < NS; ++s){
        if (t == 255) sFar[s] = far;
        double best = -1.0;
        #pragma unroll
        for (int j = 0; j < 16; ++j){
            float dx=__fsub_rn(px[j],cx), dy=__fsub_rn(py[j],cy), dz=__fsub_rn(pz[j],cz);
            float dd=__fadd_rn(__fadd_rn(__fmul_rn(dx,dx),__fmul_rn(dy,dy)),__fmul_rn(dz,dz));
            float nd = fminf(dist[j], dd);
            dist[j] = nd;
            double cand = __hiloint2double(__float_as_int(nd), (int)(~(unsigned)(pb + j)));
            best = fmax(best, cand);
        }
        u64 mine = (u64)__double_as_longlong(best);
        u64 bb = mine;
        #pragma unroll
        for (int m = 1; m < 64; m <<= 1){
            u64 o = __shfl_xor(bb, m);
            if (o > bb) bb = o;
        }
        const int par = s & 1;
        if (mine == bb) slots[par][wv] = bb;   // exactly one lane per wave
        __syncthreads();
        u64 s0 = slots[par][0], s1 = slots[par][1], s2 = slots[par][2], s3 = slots[par][3];
        u64 m01 = (s1 > s0) ? s1 : s0;
        u64 m23 = (s3 > s2) ? s3 : s2;
        u64 mm  = (m23 > m01) ? m23 : m01;
        far = (int)(~(unsigned)(mm & 0xFFFFFFFFull));
        cx = sX[far]; cy = sY[far]; cz = sZ[far];
    }
    __syncthreads();
    for (int s = t; s < NS; s += 256){
        const int f = sFar[s];
        const float x = sX[f], y = sY[f], z = sZ[f];
        float* npq = nxyz + ((size_t)b*NS + s)*3;
        npq[0]=x; npq[1]=y; npq[2]=z;
        out0[(b*3+0)*NS+s]=x; out0[(b*3+1)*NS+s]=y; out0[(b*3+2)*NS+s]=z;
    }
}

// ---------------------------------------------------------------------------
// KNN: one wave per query; exact 32nd-smallest via 32-level bitwise binary
// search on fkey (pure VALU + DPP, no LDS/atomics). Ties -> smallest index.
// ---------------------------------------------------------------------------
__global__ __launch_bounds__(256,2) void knn_kernel(const float* __restrict__ xyz,
                                                    const float* __restrict__ nxyz,
                                                    int* __restrict__ kidx)
{
    const int t = threadIdx.x, lane = t & 63, w = t >> 6;
    const int q = blockIdx.x*4 + w;
    const int b = q >> 10;
    const float* base = xyz + (size_t)b*NN*3;
    const float* qp = nxyz + (size_t)q*3;
    const float qx = qp[0], qy = qp[1], qz = qp[2];
    const float qsq = __fadd_rn(__fadd_rn(__fmul_rn(qx,qx),__fmul_rn(qy,qy)),__fmul_rn(qz,qz));

    unsigned int key[64];
    #pragma unroll
    for (int i = 0; i < 64; ++i){
        const int idx = (i<<6) + lane;
        const float* pp = base + 3*idx;
        float x = pp[0], y = pp[1], z = pp[2];
        float dot = __fadd_rn(__fadd_rn(__fmul_rn(qx,x),__fmul_rn(qy,y)),__fmul_rn(qz,z));
        float psq = __fadd_rn(__fadd_rn(__fmul_rn(x,x),__fmul_rn(y,y)),__fmul_rn(z,z));
        float d = __fadd_rn(__fadd_rn(__fmul_rn(-2.0f,dot),qsq),psq);
        key[i] = fkey(d);
    }

    unsigned int pref = 0; int need = 32;
    for (int bit = 31; bit >= 0; --bit){
        const unsigned int bound = 1u << bit;
        int c = 0;
        #pragma unroll
        for (int i = 0; i < 64; ++i) c += ((key[i] ^ pref) < bound) ? 1 : 0;
        int tot = __builtin_amdgcn_readlane(wave_incl_add(c), 63);
        if (tot < need){ need -= tot; pref |= bound; }
    }
    const unsigned int T = pref;

    int cl = 0;
    #pragma unroll
    for (int i = 0; i < 64; ++i) cl += (key[i] < T) ? 1 : 0;
    int incl_cl = wave_incl_add(cl);
    int clx = incl_cl - cl;
    int tiebase = __builtin_amdgcn_readlane(incl_cl, 63);
    int* oq = kidx + (size_t)q*NK;
    int pos = clx;
    #pragma unroll
    for (int i = 0; i < 64; ++i){
        if (key[i] < T){ oq[pos] = (i<<6) + lane; ++pos; }
    }
    int tcount = 0;
    for (int i = 0; i < 64 && tcount < need; ++i){
        u64 m = __ballot(key[i] == T);
        int myrank = (int)__popcll(m & ((1ull << lane) - 1ull));
        if ((key[i] == T) && (tcount + myrank < need))
            oq[tiebase + tcount + myrank] = (i<<6) + lane;
        tcount += (int)__popcll(m);
    }
}

// ---------------------------------------------------------------------------
// Weight transpose: Wt[m][c][o] = W_m[o][c]  (5 matrices, one launch)
// ---------------------------------------------------------------------------
__global__ __launch_bounds__(256) void wtrans_kernel(const float* __restrict__ w0,
    const float* __restrict__ w1, const float* __restrict__ w2,
    const float* __restrict__ w3, const float* __restrict__ w4,
    float* __restrict__ dst)
{
    const float* s;
    switch (blockIdx.x){
        case 0: s = w0; break; case 1: s = w1; break; case 2: s = w2; break;
        case 3: s = w3; break; default: s = w4; break;
    }
    float* d = dst + (size_t)blockIdx.x*4096;
    for (int i = threadIdx.x; i < 4096; i += 256){
        int o = i >> 6, c = i & 63;
        d[c*64 + o] = s[i];
    }
}

// ---------------------------------------------------------------------------
// Gather: x0[c][p] = features[b, kidx[p], c]   (layout [C, NP])
// ---------------------------------------------------------------------------
__global__ __launch_bounds__(256,2) void gather_kernel(const float* __restrict__ features,
                                                       const int* __restrict__ kidx,
                                                       float* __restrict__ x0)
{
    const int p = blockIdx.x*256 + threadIdx.x;
    const int b = p >> 15;
    const int idx = kidx[p];
    const float4* f = (const float4*)(features + ((size_t)b*NN + idx)*NC);
    #pragma unroll
    for (int c4 = 0; c4 < 16; ++c4){
        float4 v = f[c4];
        x0[(size_t)(4*c4+0)*NP + p] = v.x;
        x0[(size_t)(4*c4+1)*NP + p] = v.y;
        x0[(size_t)(4*c4+2)*NP + p] = v.z;
        x0[(size_t)(4*c4+3)*NP + p] = v.w;
    }
}

// ---------------------------------------------------------------------------
// Conv 1x1 (+ optional folded BN-affine + leaky on INPUT) + fused BN stats.
// o-half per block (blockIdx&1) -> weight/bias/aff addresses thread-uniform
// -> scalar (SMEM) loads, zero LDS in the K-loop. 4 pos x 32 out per thread.
// __launch_bounds__(512,2): VGPR cap 256 -> no spill (acc alone is 128).
// partials layout: [half][stat*o (64)][bp (128)]
// ---------------------------------------------------------------------------
__global__ __launch_bounds__(512,2) void conv_kernel(const float* __restrict__ in,
    float* __restrict__ out, const float* __restrict__ Wt, const float* __restrict__ bias,
    const float* __restrict__ aff, float* __restrict__ partials, const int apply_act)
{
    __shared__ float sRed[8][64];
    const int t = threadIdx.x, lane = t & 63, wv = t >> 6;
    const int bo = blockIdx.x & 1, bp = blockIdx.x >> 1;
    const int obase = bo*32;
    const int p0 = bp*2048 + wv*256 + lane;

    float acc[4][32];
    #pragma unroll
    for (int o = 0; o < 32; ++o){
        float bb = bias[obase + o];
        acc[0][o]=bb; acc[1][o]=bb; acc[2][o]=bb; acc[3][o]=bb;
    }
    #pragma unroll 2
    for (int c = 0; c < 64; ++c){
        float xv[4];
        xv[0] = in[(size_t)c*NP + p0];
        xv[1] = in[(size_t)c*NP + p0 + 64];
        xv[2] = in[(size_t)c*NP + p0 + 128];
        xv[3] = in[(size_t)c*NP + p0 + 192];
        if (apply_act){
            float sc = aff[c], sh = aff[64+c];
            #pragma unroll
            for (int j = 0; j < 4; ++j){
                float v = fmaf(sc, xv[j], sh);
                xv[j] = v >= 0.0f ? v : 0.1f*v;
            }
        }
        const float4* wr = (const float4*)(Wt + c*64 + obase);   // uniform -> s_load
        #pragma unroll
        for (int o4 = 0; o4 < 8; ++o4){
            float4 w = wr[o4];
            #pragma unroll
            for (int j = 0; j < 4; ++j){
                acc[j][4*o4+0] = fmaf(w.x, xv[j], acc[j][4*o4+0]);
                acc[j][4*o4+1] = fmaf(w.y, xv[j], acc[j][4*o4+1]);
                acc[j][4*o4+2] = fmaf(w.z, xv[j], acc[j][4*o4+2]);
                acc[j][4*o4+3] = fmaf(w.w, xv[j], acc[j][4*o4+3]);
            }
        }
    }
    #pragma unroll
    for (int o = 0; o < 32; ++o){
        float* po = out + (size_t)(obase+o)*NP + p0;
        po[0]   = acc[0][o];
        po[64]  = acc[1][o];
        po[128] = acc[2][o];
        po[192] = acc[3][o];
    }
    // fused BN stats
    #pragma unroll
    for (int o = 0; o < 32; ++o){
        float a0=acc[0][o], a1=acc[1][o], a2=acc[2][o], a3=acc[3][o];
        float s1 = (a0+a1)+(a2+a3);
        float s2 = ((a0*a0+a1*a1)+(a2*a2+a3*a3));
        float t1 = wave_sum_f(s1);
        float t2 = wave_sum_f(s2);
        if (lane == 63){ sRed[wv][o] = t1; sRed[wv][32+o] = t2; }
    }
    __syncthreads();
    if (t < 64){
        float v = 0.0f;
        #pragma unroll
        for (int w8 = 0; w8 < 8; ++w8) v += sRed[w8][t];
        partials[(size_t)bo*8192 + t*128 + bp] = v;
    }
}

// ---------------------------------------------------------------------------
// Finalize BN stats -> per-channel affine.
// ---------------------------------------------------------------------------
__global__ __launch_bounds__(64) void finalize_kernel(const float* __restrict__ partials,
    const float* __restrict__ g, const float* __restrict__ beta, float* __restrict__ aff)
{
    const int c = threadIdx.x;               // channel
    const int half = c >> 5, oo = c & 31;
    const float* p1 = partials + (size_t)half*8192 + oo*128;
    const float* p2 = partials + (size_t)half*8192 + (32+oo)*128;
    float S1 = 0.0f, S2 = 0.0f;
    #pragma unroll 8
    for (int i = 0; i < 128; ++i){ S1 += p1[i]; S2 += p2[i]; }
    float mean = S1 * (1.0f/(float)NP);
    float var  = fmaxf(S2 * (1.0f/(float)NP) - mean*mean, 0.0f);
    float sc = g[c] * rsqrtf(var + EPSBN);
    aff[c]    = sc;
    aff[64+c] = beta[c] - mean*sc;
}

// ---------------------------------------------------------------------------
__global__ __launch_bounds__(256) void resid_kernel(const float* __restrict__ v,
    const float* __restrict__ yt, float* __restrict__ x2,
    const float* __restrict__ affV, const float* __restrict__ affY)
{
    const size_t e = (size_t)blockIdx.x*256 + threadIdx.x;
    const int c = (int)(e >> 16);
    const float va = affV[c], vb = affV[64+c];
    const float ya = affY[c], yb = affY[64+c];
    const float4 vv = ((const float4*)v)[e];
    const float4 yy = ((const float4*)yt)[e];
    float4 r;
    r.x = lrelu(fmaf(va, vv.x, vb) + lrelu(fmaf(ya, yy.x, yb)));
    r.y = lrelu(fmaf(va, vv.y, vb) + lrelu(fmaf(ya, yy.y, yb)));
    r.z = lrelu(fmaf(va, vv.z, vb) + lrelu(fmaf(ya, yy.z, yb)));
    r.w = lrelu(fmaf(va, vv.w, vb) + lrelu(fmaf(ya, yy.w, yb)));
    ((float4*)x2)[e] = r;
}

// ---------------------------------------------------------------------------
__global__ __launch_bounds__(256) void final_kernel(const float* __restrict__ v2,
    const float* __restrict__ x2, const float* __restrict__ aff, float* __restrict__ out1)
{
    const int gg = blockIdx.x*256 + threadIdx.x;
    const int c = gg >> 13;
    const int bs = gg & 8191;
    const float a = aff[c], sh = aff[64+c];
    const float4* pv = (const float4*)(v2 + (size_t)c*NP + (size_t)bs*NK);
    const float4* px = (const float4*)(x2 + (size_t)c*NP + (size_t)bs*NK);
    float m = -3.0e38f;
    #pragma unroll
    for (int i = 0; i < 8; ++i){
        float4 av = pv[i], xv = px[i];
        m = fmaxf(m, lrelu(fmaf(a, av.x, sh) + xv.x));
        m = fmaxf(m, lrelu(fmaf(a, av.y, sh) + xv.y));
        m = fmaxf(m, lrelu(fmaf(a, av.z, sh) + xv.z));
        m = fmaxf(m, lrelu(fmaf(a, av.w, sh) + xv.w));
    }
    const int b = bs >> 10, s = bs & 1023;
    out1[((size_t)b*NC + c)*NS + s] = m;
}

// ---------------------------------------------------------------------------
extern "C" void kernel_launch(void* const* d_in, const int* in_sizes, int n_in,
                              void* d_out, int out_size, void* d_ws, size_t ws_size,
                              hipStream_t stream)
{
    const float* xyz      = (const float*)d_in[0];
    const float* features = (const float*)d_in[1];
    const float* w_t    = (const float*)d_in[2];
    const float* w1_0   = (const float*)d_in[3];
    const float* w2_0   = (const float*)d_in[4];
    const float* w1_1   = (const float*)d_in[5];
    const float* w2_1   = (const float*)d_in[6];
    const float* b_t    = (const float*)d_in[7];
    const float* b1_0   = (const float*)d_in[8];
    const float* b2_0   = (const float*)d_in[9];
    const float* b1_1   = (const float*)d_in[10];
    const float* b2_1   = (const float*)d_in[11];
    const float* g_t    = (const float*)d_in[12];
    const float* g1_0   = (const float*)d_in[13];
    const float* g2_0   = (const float*)d_in[14];
    const float* g1_1   = (const float*)d_in[15];
    const float* g2_1   = (const float*)d_in[16];
    const float* beta_t  = (const float*)d_in[17];
    const float* beta1_0 = (const float*)d_in[18];
    const float* beta2_0 = (const float*)d_in[19];
    const float* beta1_1 = (const float*)d_in[20];
    const float* beta2_1 = (const float*)d_in[21];

    float* out = (float*)d_out;

    float* buf0  = (float*)d_ws;
    float* buf1  = buf0 + (size_t)NC*NP;
    float* buf2  = buf1 + (size_t)NC*NP;
    float* nxyz  = buf2 + (size_t)NC*NP;                 // NB*NS*3
    int*   kidx  = (int*)(nxyz + (size_t)NB*NS*3);       // NP ints
    float* partials = (float*)(kidx + NP);               // 16384 floats
    float* affx  = partials + 16384;                     // 5*128
    float* wt    = affx + 5*128;                         // 5*4096

    wtrans_kernel<<<5, 256, 0, stream>>>(w_t, w1_0, w2_0, w1_1, w2_1, wt);
    fps_kernel<<<NB, 256, 0, stream>>>(xyz, out, nxyz);
    knn_kernel<<<NQ/4, 256, 0, stream>>>(xyz, nxyz, kidx);
    gather_kernel<<<NP/256, 256, 0, stream>>>(features, kidx, buf0);

    // stage t
    conv_kernel<<<256, 512, 0, stream>>>(buf0, buf1, wt + 0*4096, b_t, affx, partials, 0);
    finalize_kernel<<<1, 64, 0, stream>>>(partials, g_t, beta_t, affx + 0);
    // resblock 0
    conv_kernel<<<256, 512, 0, stream>>>(buf1, buf0, wt + 1*4096, b1_0, affx + 0, partials, 1);
    finalize_kernel<<<1, 64, 0, stream>>>(partials, g1_0, beta1_0, affx + 128);
    conv_kernel<<<256, 512, 0, stream>>>(buf0, buf2, wt + 2*4096, b2_0, affx + 128, partials, 1);
    finalize_kernel<<<1, 64, 0, stream>>>(partials, g2_0, beta2_0, affx + 256);
    resid_kernel<<<(NC*NP/4)/256, 256, 0, stream>>>(buf2, buf1, buf0, affx + 256, affx + 0);
    // resblock 1
    conv_kernel<<<256, 512, 0, stream>>>(buf0, buf1, wt + 3*4096, b1_1, affx, partials, 0);
    finalize_kernel<<<1, 64, 0, stream>>>(partials, g1_1, beta1_1, affx + 384);
    conv_kernel<<<256, 512, 0, stream>>>(buf1, buf2, wt + 4*4096, b2_1, affx + 384, partials, 1);
    finalize_kernel<<<1, 64, 0, stream>>>(partials, g2_1, beta2_1, affx + 512);
    // epilogue: residual + max over K
    final_kernel<<<(NC*NQ)/256, 256, 0, stream>>>(buf2, buf0, affx + 512, out + (size_t)NB*3*NS);
}

// Round 5
// 1135.082 us; speedup vs baseline: 2.0891x; 1.1690x over previous
//
#include <hip/hip_runtime.h>
#include <stdint.h>

#define NB 8
#define NN 4096
#define NC 64
#define NS 1024
#define NK 32
#define NQ (NB*NS)        /* 8192 queries */
#define NP (NQ*NK)        /* 262144 positions */
#define EPSBN 1e-5f

typedef unsigned long long u64;

__device__ __forceinline__ float lrelu(float x){ return x >= 0.0f ? x : 0.1f*x; }

// IEEE-total-order key: ascending key == ascending float
__device__ __forceinline__ unsigned int fkey(float d){
    unsigned int fb = __float_as_uint(d);
    return (fb & 0x80000000u) ? ~fb : (fb | 0x80000000u);
}

// sum-reduce (valid on lane 63 only)
__device__ __forceinline__ float wave_sum_f(float x){
    int v = __float_as_int(x);
    {int o=__builtin_amdgcn_update_dpp(0,v,0x111,0xf,0xf,true); v=__float_as_int(__int_as_float(v)+__int_as_float(o));}
    {int o=__builtin_amdgcn_update_dpp(0,v,0x112,0xf,0xf,true); v=__float_as_int(__int_as_float(v)+__int_as_float(o));}
    {int o=__builtin_amdgcn_update_dpp(0,v,0x114,0xf,0xf,true); v=__float_as_int(__int_as_float(v)+__int_as_float(o));}
    {int o=__builtin_amdgcn_update_dpp(0,v,0x118,0xf,0xf,true); v=__float_as_int(__int_as_float(v)+__int_as_float(o));}
    {int o=__builtin_amdgcn_update_dpp(0,v,0x142,0xf,0xf,true); v=__float_as_int(__int_as_float(v)+__int_as_float(o));}
    {int o=__builtin_amdgcn_update_dpp(0,v,0x143,0xf,0xf,true); v=__float_as_int(__int_as_float(v)+__int_as_float(o));}
    return __int_as_float(v);
}
// inclusive prefix-sum over 64 lanes (ints)
__device__ __forceinline__ int wave_incl_add(int x){
    int v = x;
    {int o=__builtin_amdgcn_update_dpp(0,v,0x111,0xf,0xf,true); v+=o;}
    {int o=__builtin_amdgcn_update_dpp(0,v,0x112,0xf,0xf,true); v+=o;}
    {int o=__builtin_amdgcn_update_dpp(0,v,0x114,0xf,0xf,true); v+=o;}
    {int o=__builtin_amdgcn_update_dpp(0,v,0x118,0xf,0xf,true); v+=o;}
    {int o=__builtin_amdgcn_update_dpp(0,v,0x142,0xa,0xf,true); v+=o;}
    {int o=__builtin_amdgcn_update_dpp(0,v,0x143,0xc,0xf,true); v+=o;}
    return v;
}
// max-reduce of a packed positive double across the wave, via DPP pairs
// (VALU pipe, no LDS). Result broadcast via readlane 63.
__device__ __forceinline__ double wave_max_d(double x){
    int lo = __double2loint(x), hi = __double2hiint(x);
    #define FPS_STG(ctl) { \
        int nl=__builtin_amdgcn_update_dpp(lo,lo,ctl,0xf,0xf,false); \
        int nh=__builtin_amdgcn_update_dpp(hi,hi,ctl,0xf,0xf,false); \
        double mx=fmax(__hiloint2double(hi,lo), __hiloint2double(nh,nl)); \
        lo=__double2loint(mx); hi=__double2hiint(mx); }
    FPS_STG(0x111) FPS_STG(0x112) FPS_STG(0x114) FPS_STG(0x118) FPS_STG(0x142) FPS_STG(0x143)
    #undef FPS_STG
    int flo = __builtin_amdgcn_readlane(lo, 63);
    int fhi = __builtin_amdgcn_readlane(hi, 63);
    return __hiloint2double(fhi, flo);
}

// ---------------------------------------------------------------------------
// FPS: one block/batch, 256 thr (4 waves), 16 pts/thread in regs.
// Packed argmax key: double{hi=dist_bits(>=0), lo=~idx} -> fmax is
// (dist, smaller-idx) lexicographic max. Wave reduce on VALU via DPP pairs;
// cross-wave via 4 double LDS slots (double-buffered parity).
// Bit-exact vs numpy: rn ops, ((dx2+dy2)+dz2), fminf, first-occurrence.
// ---------------------------------------------------------------------------
__global__ __launch_bounds__(256,1) void fps_kernel(const float* __restrict__ xyz,
                                                    float* __restrict__ out0,
                                                    float* __restrict__ nxyz)
{
    __shared__ float sX[NN], sY[NN], sZ[NN];
    __shared__ double slots[2][4];
    __shared__ int sFar[NS];
    const int b = blockIdx.x, t = threadIdx.x;
    const int lane = t & 63, wv = t >> 6;
    const float* base = xyz + (size_t)b*NN*3;
    for (int i = t; i < NN; i += 256){
        const float* pp = base + 3*i;
        sX[i] = pp[0]; sY[i] = pp[1]; sZ[i] = pp[2];
    }
    __syncthreads();
    float px[16], py[16], pz[16], dist[16];
    const int pb = t*16;
    #pragma unroll
    for (int j = 0; j < 16; ++j){
        px[j]=sX[pb+j]; py[j]=sY[pb+j]; pz[j]=sZ[pb+j]; dist[j]=1e10f;
    }
    int far = 0;
    float cx = sX[0], cy = sY[0], cz = sZ[0];
    for (int s = 0; s < NS; ++s){
        if (t == 255) sFar[s] = far;
        double best = -1.0;
        #pragma unroll
        for (int j = 0; j < 16; ++j){
            float dx=__fsub_rn(px[j],cx), dy=__fsub_rn(py[j],cy), dz=__fsub_rn(pz[j],cz);
            float dd=__fadd_rn(__fadd_rn(__fmul_rn(dx,dx),__fmul_rn(dy,dy)),__fmul_rn(dz,dz));
            float nd = fminf(dist[j], dd);
            dist[j] = nd;
            best = fmax(best, __hiloint2double(__float_as_int(nd), (int)(~(unsigned)(pb + j))));
        }
        double wb = wave_max_d(best);
        const int par = s & 1;
        if (lane == 0) slots[par][wv] = wb;
        __syncthreads();
        double s0 = slots[par][0], s1 = slots[par][1];
        double s2 = slots[par][2], s3 = slots[par][3];
        double mm = fmax(fmax(s0, s1), fmax(s2, s3));
        far = (int)(~(unsigned)__double2loint(mm));
        cx = sX[far]; cy = sY[far]; cz = sZ[far];
    }
    __syncthreads();
    for (int s = t; s < NS; s += 256){
        const int f = sFar[s];
        const float x = sX[f], y = sY[f], z = sZ[f];
        float* npq = nxyz + ((size_t)b*NS + s)*3;
        npq[0]=x; npq[1]=y; npq[2]=z;
        out0[(b*3+0)*NS+s]=x; out0[(b*3+1)*NS+s]=y; out0[(b*3+2)*NS+s]=z;
    }
}

// ---------------------------------------------------------------------------
// KNN: one wave per query; exact 32nd-smallest via 32-level bitwise binary
// search on fkey (pure VALU + DPP, no LDS/atomics). Ties -> smallest index.
// ---------------------------------------------------------------------------
__global__ __launch_bounds__(256,2) void knn_kernel(const float* __restrict__ xyz,
                                                    const float* __restrict__ nxyz,
                                                    int* __restrict__ kidx)
{
    const int t = threadIdx.x, lane = t & 63, w = t >> 6;
    const int q = blockIdx.x*4 + w;
    const int b = q >> 10;
    const float* base = xyz + (size_t)b*NN*3;
    const float* qp = nxyz + (size_t)q*3;
    const float qx = qp[0], qy = qp[1], qz = qp[2];
    const float qsq = __fadd_rn(__fadd_rn(__fmul_rn(qx,qx),__fmul_rn(qy,qy)),__fmul_rn(qz,qz));

    unsigned int key[64];
    #pragma unroll
    for (int i = 0; i < 64; ++i){
        const int idx = (i<<6) + lane;
        const float* pp = base + 3*idx;
        float x = pp[0], y = pp[1], z = pp[2];
        float dot = __fadd_rn(__fadd_rn(__fmul_rn(qx,x),__fmul_rn(qy,y)),__fmul_rn(qz,z));
        float psq = __fadd_rn(__fadd_rn(__fmul_rn(x,x),__fmul_rn(y,y)),__fmul_rn(z,z));
        float d = __fadd_rn(__fadd_rn(__fmul_rn(-2.0f,dot),qsq),psq);
        key[i] = fkey(d);
    }

    unsigned int pref = 0; int need = 32;
    for (int bit = 31; bit >= 0; --bit){
        const unsigned int bound = 1u << bit;
        int c = 0;
        #pragma unroll
        for (int i = 0; i < 64; ++i) c += ((key[i] ^ pref) < bound) ? 1 : 0;
        int tot = __builtin_amdgcn_readlane(wave_incl_add(c), 63);
        if (tot < need){ need -= tot; pref |= bound; }
    }
    const unsigned int T = pref;

    int cl = 0;
    #pragma unroll
    for (int i = 0; i < 64; ++i) cl += (key[i] < T) ? 1 : 0;
    int incl_cl = wave_incl_add(cl);
    int clx = incl_cl - cl;
    int tiebase = __builtin_amdgcn_readlane(incl_cl, 63);
    int* oq = kidx + (size_t)q*NK;
    int pos = clx;
    #pragma unroll
    for (int i = 0; i < 64; ++i){
        if (key[i] < T){ oq[pos] = (i<<6) + lane; ++pos; }
    }
    int tcount = 0;
    for (int i = 0; i < 64 && tcount < need; ++i){
        u64 m = __ballot(key[i] == T);
        int myrank = (int)__popcll(m & ((1ull << lane) - 1ull));
        if ((key[i] == T) && (tcount + myrank < need))
            oq[tiebase + tcount + myrank] = (i<<6) + lane;
        tcount += (int)__popcll(m);
    }
}

// ---------------------------------------------------------------------------
// Weight transpose: Wt[m][c][o] = W_m[o][c]  (5 matrices, one launch)
// ---------------------------------------------------------------------------
__global__ __launch_bounds__(256) void wtrans_kernel(const float* __restrict__ w0,
    const float* __restrict__ w1, const float* __restrict__ w2,
    const float* __restrict__ w3, const float* __restrict__ w4,
    float* __restrict__ dst)
{
    const float* s;
    switch (blockIdx.x){
        case 0: s = w0; break; case 1: s = w1; break; case 2: s = w2; break;
        case 3: s = w3; break; default: s = w4; break;
    }
    float* d = dst + (size_t)blockIdx.x*4096;
    for (int i = threadIdx.x; i < 4096; i += 256){
        int o = i >> 6, c = i & 63;
        d[c*64 + o] = s[i];
    }
}

// ---------------------------------------------------------------------------
// Gather: x0[c][p] = features[b, kidx[p], c]   (layout [C, NP])
// ---------------------------------------------------------------------------
__global__ __launch_bounds__(256,2) void gather_kernel(const float* __restrict__ features,
                                                       const int* __restrict__ kidx,
                                                       float* __restrict__ x0)
{
    const int p = blockIdx.x*256 + threadIdx.x;
    const int b = p >> 15;
    const int idx = kidx[p];
    const float4* f = (const float4*)(features + ((size_t)b*NN + idx)*NC);
    #pragma unroll
    for (int c4 = 0; c4 < 16; ++c4){
        float4 v = f[c4];
        x0[(size_t)(4*c4+0)*NP + p] = v.x;
        x0[(size_t)(4*c4+1)*NP + p] = v.y;
        x0[(size_t)(4*c4+2)*NP + p] = v.z;
        x0[(size_t)(4*c4+3)*NP + p] = v.w;
    }
}

// ---------------------------------------------------------------------------
// Conv 1x1 + fused BN stats. If pin != null: compute input affine in-kernel
// from producer partials (+g,+beta), apply affine+leaky on input.
// o-half per block -> weight addresses uniform (s_load). 4 pos x 32 out/thr.
// partials layout: [half(2)][bp(128)][stat(64)]  (stat 0..31 sum, 32..63 sq)
// ---------------------------------------------------------------------------
__global__ __launch_bounds__(512,2) void conv_kernel(const float* __restrict__ in,
    float* __restrict__ out, const float* __restrict__ Wt, const float* __restrict__ bias,
    const float* __restrict__ pin, const float* __restrict__ g,
    const float* __restrict__ beta, float* __restrict__ affout,
    float* __restrict__ pout)
{
    __shared__ float sAff[128];
    __shared__ float sRed[8][64];
    const int t = threadIdx.x, lane = t & 63, wv = t >> 6;
    const int bo = blockIdx.x & 1, bp = blockIdx.x >> 1;
    const int obase = bo*32;
    const int p0 = bp*2048 + wv*256 + lane;
    const int apply_act = (pin != nullptr);

    if (apply_act){
        if (t < 64){
            const int half = t >> 5, oo = t & 31;
            const float* pb1 = pin + (size_t)half*8192;
            float S1 = 0.0f, S2 = 0.0f;
            #pragma unroll 4
            for (int i = 0; i < 128; ++i){
                S1 += pb1[i*64 + oo];
                S2 += pb1[i*64 + 32 + oo];
            }
            float mean = S1 * (1.0f/(float)NP);
            float var  = fmaxf(S2 * (1.0f/(float)NP) - mean*mean, 0.0f);
            float sc = g[t] * rsqrtf(var + EPSBN);
            sAff[t]    = sc;
            sAff[64+t] = beta[t] - mean*sc;
            if (affout){ affout[t] = sc; affout[64+t] = sAff[64+t]; }
        }
        __syncthreads();
    }

    float acc[4][32];
    #pragma unroll
    for (int o = 0; o < 32; ++o){
        float bb = bias[obase + o];
        acc[0][o]=bb; acc[1][o]=bb; acc[2][o]=bb; acc[3][o]=bb;
    }
    #pragma unroll 2
    for (int c = 0; c < 64; ++c){
        float xv[4];
        xv[0] = in[(size_t)c*NP + p0];
        xv[1] = in[(size_t)c*NP + p0 + 64];
        xv[2] = in[(size_t)c*NP + p0 + 128];
        xv[3] = in[(size_t)c*NP + p0 + 192];
        if (apply_act){
            float sc = sAff[c], sh = sAff[64+c];
            #pragma unroll
            for (int j = 0; j < 4; ++j){
                float v = fmaf(sc, xv[j], sh);
                xv[j] = v >= 0.0f ? v : 0.1f*v;
            }
        }
        const float4* wr = (const float4*)(Wt + c*64 + obase);   // uniform -> s_load
        #pragma unroll
        for (int o4 = 0; o4 < 8; ++o4){
            float4 w = wr[o4];
            #pragma unroll
            for (int j = 0; j < 4; ++j){
                acc[j][4*o4+0] = fmaf(w.x, xv[j], acc[j][4*o4+0]);
                acc[j][4*o4+1] = fmaf(w.y, xv[j], acc[j][4*o4+1]);
                acc[j][4*o4+2] = fmaf(w.z, xv[j], acc[j][4*o4+2]);
                acc[j][4*o4+3] = fmaf(w.w, xv[j], acc[j][4*o4+3]);
            }
        }
    }
    #pragma unroll
    for (int o = 0; o < 32; ++o){
        float* po = out + (size_t)(obase+o)*NP + p0;
        po[0]   = acc[0][o];
        po[64]  = acc[1][o];
        po[128] = acc[2][o];
        po[192] = acc[3][o];
    }
    // fused BN stats
    #pragma unroll
    for (int o = 0; o < 32; ++o){
        float a0=acc[0][o], a1=acc[1][o], a2=acc[2][o], a3=acc[3][o];
        float s1 = (a0+a1)+(a2+a3);
        float s2 = ((a0*a0+a1*a1)+(a2*a2+a3*a3));
        float t1 = wave_sum_f(s1);
        float t2 = wave_sum_f(s2);
        if (lane == 63){ sRed[wv][o] = t1; sRed[wv][32+o] = t2; }
    }
    __syncthreads();
    if (t < 64){
        float v = 0.0f;
        #pragma unroll
        for (int w8 = 0; w8 < 8; ++w8) v += sRed[w8][t];
        pout[(size_t)bo*8192 + bp*64 + t] = v;
    }
}

// ---------------------------------------------------------------------------
// Residual: x2 = leaky(affV(v) + leaky(affY(yt))). affV computed in-kernel
// from partials of v's conv; affY read from affx. Uniform channel per block.
// ---------------------------------------------------------------------------
__global__ __launch_bounds__(256,2) void resid_kernel(const float* __restrict__ v,
    const float* __restrict__ yt, float* __restrict__ x2,
    const float* __restrict__ pin, const float* __restrict__ g,
    const float* __restrict__ beta, const float* __restrict__ affY)
{
    __shared__ float sPr[4];
    const int t = threadIdx.x, lane = t & 63, wv = t >> 6;
    const int c = blockIdx.x >> 4;                 // 16 blocks per channel
    if (t < 128){
        const int half = c >> 5, oo = c & 31;
        float a1 = pin[(size_t)half*8192 + t*64 + oo];
        float a2 = pin[(size_t)half*8192 + t*64 + 32 + oo];
        float r1 = wave_sum_f(a1);
        float r2 = wave_sum_f(a2);
        if (lane == 63){ sPr[wv*2] = r1; sPr[wv*2+1] = r2; }
    }
    __syncthreads();
    float S1 = sPr[0] + sPr[2], S2 = sPr[1] + sPr[3];
    float mean = S1 * (1.0f/(float)NP);
    float var  = fmaxf(S2 * (1.0f/(float)NP) - mean*mean, 0.0f);
    const float va = g[c] * rsqrtf(var + EPSBN);
    const float vb = beta[c] - mean*va;
    const float ya = affY[c], yb = affY[64+c];
    const size_t e0 = (size_t)blockIdx.x*4096 + t;
    #pragma unroll
    for (int i = 0; i < 16; ++i){
        const size_t e = e0 + i*256;
        const float4 vv = ((const float4*)v)[e];
        const float4 yy = ((const float4*)yt)[e];
        float4 r;
        r.x = lrelu(fmaf(va, vv.x, vb) + lrelu(fmaf(ya, yy.x, yb)));
        r.y = lrelu(fmaf(va, vv.y, vb) + lrelu(fmaf(ya, yy.y, yb)));
        r.z = lrelu(fmaf(va, vv.z, vb) + lrelu(fmaf(ya, yy.z, yb)));
        r.w = lrelu(fmaf(va, vv.w, vb) + lrelu(fmaf(ya, yy.w, yb)));
        ((float4*)x2)[e] = r;
    }
}

// ---------------------------------------------------------------------------
// Final: x3 = leaky(aff(v2) + x2); out1[b,c,s] = max_k x3. Aff in-kernel.
// ---------------------------------------------------------------------------
__global__ __launch_bounds__(256,2) void final_kernel(const float* __restrict__ v2,
    const float* __restrict__ x2, const float* __restrict__ pin,
    const float* __restrict__ g, const float* __restrict__ beta,
    float* __restrict__ out1)
{
    __shared__ float sPr[4];
    const int t = threadIdx.x, lane = t & 63, wv = t >> 6;
    const int c = blockIdx.x >> 5;                 // 32 blocks per channel
    if (t < 128){
        const int half = c >> 5, oo = c & 31;
        float a1 = pin[(size_t)half*8192 + t*64 + oo];
        float a2 = pin[(size_t)half*8192 + t*64 + 32 + oo];
        float r1 = wave_sum_f(a1);
        float r2 = wave_sum_f(a2);
        if (lane == 63){ sPr[wv*2] = r1; sPr[wv*2+1] = r2; }
    }
    __syncthreads();
    float S1 = sPr[0] + sPr[2], S2 = sPr[1] + sPr[3];
    float mean = S1 * (1.0f/(float)NP);
    float var  = fmaxf(S2 * (1.0f/(float)NP) - mean*mean, 0.0f);
    const float a = g[c] * rsqrtf(var + EPSBN);
    const float sh = beta[c] - mean*a;

    const int gg = blockIdx.x*256 + t;
    const int bs = gg & 8191;
    const float4* pv = (const float4*)(v2 + (size_t)c*NP + (size_t)bs*NK);
    const float4* px = (const float4*)(x2 + (size_t)c*NP + (size_t)bs*NK);
    float m = -3.0e38f;
    #pragma unroll
    for (int i = 0; i < 8; ++i){
        float4 av = pv[i], xv = px[i];
        m = fmaxf(m, lrelu(fmaf(a, av.x, sh) + xv.x));
        m = fmaxf(m, lrelu(fmaf(a, av.y, sh) + xv.y));
        m = fmaxf(m, lrelu(fmaf(a, av.z, sh) + xv.z));
        m = fmaxf(m, lrelu(fmaf(a, av.w, sh) + xv.w));
    }
    const int b = bs >> 10, s = bs & 1023;
    out1[((size_t)b*NC + c)*NS + s] = m;
}

// ---------------------------------------------------------------------------
extern "C" void kernel_launch(void* const* d_in, const int* in_sizes, int n_in,
                              void* d_out, int out_size, void* d_ws, size_t ws_size,
                              hipStream_t stream)
{
    const float* xyz      = (const float*)d_in[0];
    const float* features = (const float*)d_in[1];
    const float* w_t    = (const float*)d_in[2];
    const float* w1_0   = (const float*)d_in[3];
    const float* w2_0   = (const float*)d_in[4];
    const float* w1_1   = (const float*)d_in[5];
    const float* w2_1   = (const float*)d_in[6];
    const float* b_t    = (const float*)d_in[7];
    const float* b1_0   = (const float*)d_in[8];
    const float* b2_0   = (const float*)d_in[9];
    const float* b1_1   = (const float*)d_in[10];
    const float* b2_1   = (const float*)d_in[11];
    const float* g_t    = (const float*)d_in[12];
    const float* g1_0   = (const float*)d_in[13];
    const float* g2_0   = (const float*)d_in[14];
    const float* g1_1   = (const float*)d_in[15];
    const float* g2_1   = (const float*)d_in[16];
    const float* beta_t  = (const float*)d_in[17];
    const float* beta1_0 = (const float*)d_in[18];
    const float* beta2_0 = (const float*)d_in[19];
    const float* beta1_1 = (const float*)d_in[20];
    const float* beta2_1 = (const float*)d_in[21];

    float* out = (float*)d_out;

    float* buf0  = (float*)d_ws;
    float* buf1  = buf0 + (size_t)NC*NP;
    float* buf2  = buf1 + (size_t)NC*NP;
    float* nxyz  = buf2 + (size_t)NC*NP;                 // NB*NS*3
    int*   kidx  = (int*)(nxyz + (size_t)NB*NS*3);       // NP ints
    float* pT    = (float*)(kidx + NP);                  // 5 x 16384 partials
    float* p10   = pT  + 16384;
    float* p20   = p10 + 16384;
    float* p11   = p20 + 16384;
    float* p21   = p11 + 16384;
    float* affx  = p21 + 16384;                          // 128 (aff_t for resid)
    float* wt    = affx + 128;                           // 5*4096

    wtrans_kernel<<<5, 256, 0, stream>>>(w_t, w1_0, w2_0, w1_1, w2_1, wt);
    fps_kernel<<<NB, 256, 0, stream>>>(xyz, out, nxyz);
    knn_kernel<<<NQ/4, 256, 0, stream>>>(xyz, nxyz, kidx);
    gather_kernel<<<NP/256, 256, 0, stream>>>(features, kidx, buf0);

    // stage t  (no input affine)
    conv_kernel<<<256, 512, 0, stream>>>(buf0, buf1, wt + 0*4096, b_t,
                                         nullptr, nullptr, nullptr, nullptr, pT);
    // resblock 0
    conv_kernel<<<256, 512, 0, stream>>>(buf1, buf0, wt + 1*4096, b1_0,
                                         pT, g_t, beta_t, affx, p10);
    conv_kernel<<<256, 512, 0, stream>>>(buf0, buf2, wt + 2*4096, b2_0,
                                         p10, g1_0, beta1_0, nullptr, p20);
    resid_kernel<<<1024, 256, 0, stream>>>(buf2, buf1, buf0,
                                           p20, g2_0, beta2_0, affx);
    // resblock 1  (input already activated)
    conv_kernel<<<256, 512, 0, stream>>>(buf0, buf1, wt + 3*4096, b1_1,
                                         nullptr, nullptr, nullptr, nullptr, p11);
    conv_kernel<<<256, 512, 0, stream>>>(buf1, buf2, wt + 4*4096, b2_1,
                                         p11, g1_1, beta1_1, nullptr, p21);
    // epilogue: residual + max over K
    final_kernel<<<2048, 256, 0, stream>>>(buf2, buf0, p21, g2_1, beta2_1,
                                           out + (size_t)NB*3*NS);
}